// Round 5
// baseline (1575.401 us; speedup 1.0000x reference)
//
#include <hip/hip_runtime.h>
#include <hip/hip_bf16.h>
#include <hip/hip_cooperative_groups.h>
#include <math.h>

namespace cg = cooperative_groups;

#define BB 4
#define NN 1024
#define KK 128
#define DD 32
#define LL 3
#define EH 130
#define EHP 132

typedef float f32x4 __attribute__((ext_vector_type(4)));
typedef short s16x8 __attribute__((ext_vector_type(8)));

__device__ __forceinline__ float lrelu(float x) { return fmaxf(x, 0.1f * x); }

__device__ __forceinline__ unsigned pk2(float a, float b) {   // v_cvt_pk_bf16_f32 (RNE)
    __hip_bfloat162 h = __float22bfloat162_rn(float2{a, b});
    return *(unsigned*)&h;
}
__device__ __forceinline__ unsigned short bf16_hu(float v) {
    return (unsigned short)((__float_as_uint(v) + 0x8000u) >> 16);
}
__device__ __forceinline__ unsigned short bf16_rne(float v) {
    unsigned u = __float_as_uint(v);
    return (unsigned short)((u + 0x7fffu + ((u >> 16) & 1u)) >> 16);
}

// ---- exact wave-level KNN select for one node (4-pass LDS radix select; R4-verified) ----
__device__ __forceinline__ void knn_select(const float2* __restrict__ cbp, int i, int lane,
                                           unsigned* __restrict__ hist,   // per-wave 256 uints (LDS)
                                           int* __restrict__ nb) {
    const float2 ci = cbp[i];
    unsigned k[16];
#pragma unroll
    for (int s = 0; s < 16; s++) {
        float2 cj = cbp[lane + 64 * s];
        float dx = ci.x - cj.x, dy = ci.y - cj.y;
        float d = __fadd_rn(__fmul_rn(dx, dx), __fmul_rn(dy, dy));
        k[s] = __float_as_uint(d);
    }
    unsigned prefix = 0u;
    unsigned r = KK - 1;
#pragma unroll
    for (int pass = 0; pass < 4; pass++) {
        const int sh = 24 - 8 * pass;
        const unsigned mpref = (pass == 0) ? 0u : (0xFFFFFFFFu << (sh + 8));
        ((uint4*)hist)[lane] = uint4{0u, 0u, 0u, 0u};
        __threadfence_block();
#pragma unroll
        for (int s = 0; s < 16; s++) {
            if ((k[s] & mpref) == prefix)
                atomicAdd(&hist[(k[s] >> sh) & 255u], 1u);
        }
        __threadfence_block();
        const uint4 h = ((const uint4*)hist)[lane];
        const unsigned partial = h.x + h.y + h.z + h.w;
        unsigned incl = partial;
#pragma unroll
        for (int off = 1; off < 64; off <<= 1) {
            unsigned v = __shfl_up(incl, off, 64);
            if (lane >= off) incl += v;
        }
        const unsigned excl = incl - partial;
        const bool own = (r >= excl) && (r < incl);
        unsigned enc = 0u;
        if (own) {
            unsigned hh[4] = {h.x, h.y, h.z, h.w};
            unsigned e = excl;
            int bin = -1;
#pragma unroll
            for (int ii = 0; ii < 4; ii++) {
                if (bin < 0) {
                    if (r < e + hh[ii]) bin = ii;
                    else e += hh[ii];
                }
            }
            enc = (((unsigned)(4 * lane + bin)) << 16) | (r - e);
        }
        const unsigned long long mk = __ballot(own);
        const int src = __ffsll((unsigned long long)mk) - 1;
        enc = __shfl(enc, src, 64);
        prefix |= (enc >> 16) << sh;
        r = enc & 0xFFFFu;
    }
    const unsigned dstar = prefix;

    const unsigned long long below = (1ull << lane) - 1ull;
    unsigned run = 0;
#pragma unroll
    for (int s = 0; s < 16; s++) {
        unsigned long long m = __ballot(k[s] < dstar);
        if (k[s] < dstar) nb[run + (unsigned)__popcll(m & below)] = lane + 64 * s;
        run += (unsigned)__popcll(m);
    }
    const int need = KK - (int)run;   // >= 1
    unsigned tie = 0;
    for (int s = 0; s < 16 && (int)tie < need; s++) {
        unsigned long long m = __ballot(k[s] == dstar);
        if (k[s] == dstar) {
            unsigned r2 = tie + (unsigned)__popcll(m & below);
            if ((int)r2 < need) nb[run + r2] = lane + 64 * s;
        }
        tie += (unsigned)__popcll(m);
    }
}

// ---- shared-memory layout for the layer body ----
struct SharedMem {
    float shi[EHP];
    float sw65[EHP];
    unsigned short smA[4 * 32 * 32];
    float sx0[128], sx1[128], su[128], sv[128], srd[128];
    int snb[128];
    float sgw[DD], sfi[DD];
    float sc1b[128], sc2w[128];
    float redm[4][DD], redc[4][2];
    float sni[2 * DD], shd[2 * DD];
    float sp1[4][2 * DD], sp2[4][DD];
};

// ---- full verified layer body (R4), parameterized by node; safe to call in a loop ----
__device__ __forceinline__ void layer_body(SharedMem& S, int node,
    const float* __restrict__ feats_in, const float* __restrict__ coors_in,
    const int*   __restrict__ nbr,
    const float* __restrict__ HI, const float* __restrict__ HJ,
    const float* __restrict__ w65,
    const unsigned short* __restrict__ e2f,
    const unsigned short* __restrict__ c1f,
    const float* __restrict__ gw, const float* __restrict__ gb,
    const float* __restrict__ c1b, const float* __restrict__ c2w, const float* __restrict__ c2b,
    const float* __restrict__ n1w, const float* __restrict__ n1b,
    const float* __restrict__ n2w, const float* __restrict__ n2b,
    const float* __restrict__ scale,
    float* __restrict__ feats_out, float* __restrict__ coors_out) {
    const int b = node >> 10;
    const int t = threadIdx.x;
    const int lane = t & 63, wid = t >> 6;
    const int ln = lane & 15, q = lane >> 4;
    const int rowbase = wid * 32;

    __syncthreads();   // protect shared reuse across sequential calls

    for (int u = t; u < EHP; u += 256) {
        S.shi[u] = HI[(size_t)node * EHP + u];
        S.sw65[u] = (u < EH) ? w65[u] : 0.f;
    }
    if (t < DD) { S.sfi[t] = feats_in[node * DD + t]; S.sgw[t] = gw[t]; }
    if (t >= 128) { S.sc1b[t - 128] = c1b[t - 128]; S.sc2w[t - 128] = c2w[t - 128]; }
    __syncthreads();

    const float cix = coors_in[node * 2], ciy = coors_in[node * 2 + 1];
    if (t < 128) {
        const int j = nbr[(size_t)node * KK + t];
        S.snb[t] = j;
        const float2 cj = *(const float2*)(coors_in + ((size_t)(b * NN) + j) * 2);
        const float dx = cix - cj.x, dy = ciy - cj.y;
        const float rd = __fadd_rn(__fmul_rn(dx, dx), __fmul_rn(dy, dy));
        S.srd[t] = rd;
        const float nrm = fmaxf(sqrtf(rd), 1e-8f);
        const float s = scale[0] / nrm;
        S.su[t] = dx * s;
        S.sv[t] = dy * s;
        const float2 hjt = *(const float2*)(HJ + ((size_t)(b * NN) + j) * EHP + 128);
        S.sx0[t] = lrelu(S.shi[128] + hjt.x + rd * S.sw65[128]);
        S.sx1[t] = lrelu(S.shi[129] + hjt.y + rd * S.sw65[129]);
    }
    __syncthreads();

    float rdR[2];
    const float* hjb[2];
#pragma unroll
    for (int mt = 0; mt < 2; mt++) {
        const int row = rowbase + mt * 16 + ln;
        rdR[mt] = S.srd[row];
        hjb[mt] = HJ + ((size_t)(b * NN) + S.snb[row]) * EHP;
    }

    const float4* shi4 = (const float4*)S.shi;
    const float4* sw4  = (const float4*)S.sw65;

    const f32x4 zz = {0.f, 0.f, 0.f, 0.f};
    f32x4 accA[2][2];
    accA[0][0] = zz; accA[0][1] = zz; accA[1][0] = zz; accA[1][1] = zz;

    float4 ha[2], hbv[2];
#pragma unroll
    for (int mt = 0; mt < 2; mt++) {
        const float4* hjp = (const float4*)(hjb[mt] + q * 8);
        ha[mt] = hjp[0];
        hbv[mt] = hjp[1];
    }
    s16x8 bcur0 = *(const s16x8*)(e2f + (0 * 64 + lane) * 8);
    s16x8 bcur1 = *(const s16x8*)(e2f + (1 * 64 + lane) * 8);

#pragma unroll 1
    for (int c = 0; c < 4; c++) {
        s16x8 bn0 = *(const s16x8*)(e2f + (((c + 1) * 2 + 0) * 64 + lane) * 8);
        s16x8 bn1 = *(const s16x8*)(e2f + (((c + 1) * 2 + 1) * 64 + lane) * 8);
        float4 nha[2], nhb[2];
        if (c < 3) {
#pragma unroll
            for (int mt = 0; mt < 2; mt++) {
                const float4* hjp = (const float4*)(hjb[mt] + (c + 1) * 32 + q * 8);
                nha[mt] = hjp[0];
                nhb[mt] = hjp[1];
            }
        }
        const int kb = c * 8 + q * 2;
        const float4 hi0 = shi4[kb], hi1 = shi4[kb + 1];
        const float4 wv0 = sw4[kb],  wv1 = sw4[kb + 1];
#pragma unroll
        for (int mt = 0; mt < 2; mt++) {
            const float r = rdR[mt];
            union { s16x8 v; unsigned u[4]; } A;
            A.u[0] = pk2(lrelu(hi0.x + ha[mt].x + r * wv0.x), lrelu(hi0.y + ha[mt].y + r * wv0.y));
            A.u[1] = pk2(lrelu(hi0.z + ha[mt].z + r * wv0.z), lrelu(hi0.w + ha[mt].w + r * wv0.w));
            A.u[2] = pk2(lrelu(hi1.x + hbv[mt].x + r * wv1.x), lrelu(hi1.y + hbv[mt].y + r * wv1.y));
            A.u[3] = pk2(lrelu(hi1.z + hbv[mt].z + r * wv1.z), lrelu(hi1.w + hbv[mt].w + r * wv1.w));
            accA[mt][0] = __builtin_amdgcn_mfma_f32_16x16x32_bf16(A.v, bcur0, accA[mt][0], 0, 0, 0);
            accA[mt][1] = __builtin_amdgcn_mfma_f32_16x16x32_bf16(A.v, bcur1, accA[mt][1], 0, 0, 0);
        }
#pragma unroll
        for (int mt = 0; mt < 2; mt++) { ha[mt] = nha[mt]; hbv[mt] = nhb[mt]; }
        bcur0 = bn0; bcur1 = bn1;
    }

    {
#pragma unroll
        for (int mt = 0; mt < 2; mt++) {
            const int row = rowbase + mt * 16 + ln;
            union { s16x8 v; unsigned u[4]; } A;
            const unsigned p0 = pk2(S.sx0[row], S.sx1[row]);
            A.u[0] = (q == 0) ? p0 : 0u;
            A.u[1] = (q == 0) ? 0x00003f80u : 0u;   // bf16(1.0) in low half
            A.u[2] = 0u;
            A.u[3] = 0u;
            accA[mt][0] = __builtin_amdgcn_mfma_f32_16x16x32_bf16(A.v, bcur0, accA[mt][0], 0, 0, 0);
            accA[mt][1] = __builtin_amdgcn_mfma_f32_16x16x32_bf16(A.v, bcur1, accA[mt][1], 0, 0, 0);
        }
    }

    s16x8 cfr[8];
#pragma unroll
    for (int g8 = 0; g8 < 8; g8++)
        cfr[g8] = *(const s16x8*)(c1f + (g8 * 64 + lane) * 8);

#pragma unroll
    for (int mt = 0; mt < 2; mt++)
#pragma unroll
        for (int nt = 0; nt < 2; nt++)
#pragma unroll
            for (int r = 0; r < 4; r++)
                accA[mt][nt][r] = lrelu(accA[mt][nt][r]);

    const float gbv = gb[0];
#pragma unroll
    for (int mt = 0; mt < 2; mt++) {
        float p[4];
#pragma unroll
        for (int r = 0; r < 4; r++)
            p[r] = accA[mt][0][r] * S.sgw[ln] + accA[mt][1][r] * S.sgw[16 + ln];
#pragma unroll
        for (int off = 1; off <= 8; off <<= 1)
#pragma unroll
            for (int r = 0; r < 4; r++) p[r] += __shfl_xor(p[r], off);
#pragma unroll
        for (int r = 0; r < 4; r++) {
            const float g = 1.f / (1.f + __expf(-(p[r] + gbv)));
            accA[mt][0][r] *= g;
            accA[mt][1][r] *= g;
        }
    }

    float mi0 = 0.f, mi1 = 0.f;
#pragma unroll
    for (int mt = 0; mt < 2; mt++)
#pragma unroll
        for (int r = 0; r < 4; r++) { mi0 += accA[mt][0][r]; mi1 += accA[mt][1][r]; }
    mi0 += __shfl_xor(mi0, 16); mi0 += __shfl_xor(mi0, 32);
    mi1 += __shfl_xor(mi1, 16); mi1 += __shfl_xor(mi1, 32);
    if (lane < 16) { S.redm[wid][lane] = mi0; S.redm[wid][16 + lane] = mi1; }

    unsigned short* smw = S.smA + wid * (32 * 32);
#pragma unroll
    for (int mt = 0; mt < 2; mt++)
#pragma unroll
        for (int nt = 0; nt < 2; nt++)
#pragma unroll
            for (int r = 0; r < 4; r++) {
                const int prow = (r << 3) | (4 * mt + q);
                smw[prow * 32 + nt * 16 + ln] = bf16_hu(accA[mt][nt][r]);
            }

    s16x8 a4[2];
#pragma unroll
    for (int mt = 0; mt < 2; mt++) {
        const int prow = ((ln & 3) << 3) | (4 * mt + (ln >> 2));
        a4[mt] = *(const s16x8*)(smw + prow * 32 + q * 8);
    }

    float cacc[2][4];
#pragma unroll
    for (int mt = 0; mt < 2; mt++)
#pragma unroll
        for (int r = 0; r < 4; r++) cacc[mt][r] = 0.f;

#pragma unroll
    for (int g = 0; g < 4; g++) {
        const float cb0 = S.sc1b[(2 * g + 0) * 16 + ln];
        const float cb1 = S.sc1b[(2 * g + 1) * 16 + ln];
        const f32x4 ci0 = {cb0, cb0, cb0, cb0};
        const f32x4 ci1 = {cb1, cb1, cb1, cb1};
        f32x4 c20[2], c21[2];
#pragma unroll
        for (int mt = 0; mt < 2; mt++) {
            c20[mt] = __builtin_amdgcn_mfma_f32_16x16x32_bf16(a4[mt], cfr[2 * g + 0], ci0, 0, 0, 0);
            c21[mt] = __builtin_amdgcn_mfma_f32_16x16x32_bf16(a4[mt], cfr[2 * g + 1], ci1, 0, 0, 0);
        }
#pragma unroll
        for (int h = 0; h < 2; h++) {
            const float c2wv = S.sc2w[(2 * g + h) * 16 + ln];
#pragma unroll
            for (int mt = 0; mt < 2; mt++)
#pragma unroll
                for (int r = 0; r < 4; r++) {
                    const float v = (h ? c21[mt][r] : c20[mt][r]);
                    cacc[mt][r] = fmaf(lrelu(v), c2wv, cacc[mt][r]);
                }
        }
    }
#pragma unroll
    for (int off = 1; off <= 8; off <<= 1)
#pragma unroll
        for (int mt = 0; mt < 2; mt++)
#pragma unroll
            for (int r = 0; r < 4; r++) cacc[mt][r] += __shfl_xor(cacc[mt][r], off);

    const float c2bv = c2b[0];
    float vxp = 0.f, vyp = 0.f;
    if (ln == 0) {
#pragma unroll
        for (int mt = 0; mt < 2; mt++)
#pragma unroll
            for (int r = 0; r < 4; r++) {
                const int row = rowbase + mt * 16 + q * 4 + r;
                const float cw = cacc[mt][r] + c2bv;
                vxp = fmaf(cw, S.su[row], vxp);
                vyp = fmaf(cw, S.sv[row], vyp);
            }
    }
    vxp += __shfl_xor(vxp, 16); vxp += __shfl_xor(vxp, 32);
    vyp += __shfl_xor(vyp, 16); vyp += __shfl_xor(vyp, 32);
    if (lane == 0) { S.redc[wid][0] = vxp; S.redc[wid][1] = vyp; }

    __syncthreads();
    if (t < DD) {
        S.sni[t] = S.sfi[t];
        S.sni[DD + t] = S.redm[0][t] + S.redm[1][t] + S.redm[2][t] + S.redm[3][t];
    }
    __syncthreads();
    {
        const int o = t & 63, p = t >> 6;
        float a = 0.f;
#pragma unroll
        for (int k = 0; k < 16; k++) a = fmaf(S.sni[p * 16 + k], n1w[(p * 16 + k) * 64 + o], a);
        S.sp1[p][o] = a;
    }
    __syncthreads();
    if (t < 2 * DD)
        S.shd[t] = lrelu(n1b[t] + ((S.sp1[0][t] + S.sp1[1][t]) + (S.sp1[2][t] + S.sp1[3][t])));
    __syncthreads();
    if (t < 128) {
        const int o = t & 31, p = t >> 5;
        float a = 0.f;
#pragma unroll
        for (int k = 0; k < 16; k++) a = fmaf(S.shd[p * 16 + k], n2w[(p * 16 + k) * DD + o], a);
        S.sp2[p][o] = a;
    }
    __syncthreads();
    if (t < DD)
        feats_out[node * DD + t] =
            n2b[t] + ((S.sp2[0][t] + S.sp2[1][t]) + (S.sp2[2][t] + S.sp2[3][t])) + S.sfi[t];
    if (t == 0) {
        coors_out[node * 2]     = cix + S.redc[0][0] + S.redc[1][0] + S.redc[2][0] + S.redc[3][0];
        coors_out[node * 2 + 1] = ciy + S.redc[0][1] + S.redc[1][1] + S.redc[2][1] + S.redc[3][1];
    }
}

// =========================== persistent cooperative megakernel ===========================
struct MegaArgs {
    const float *feat, *coor;
    const float *embed_w, *embed_b, *e1w, *e1b, *e2w, *e2b, *gate_w, *gate_b;
    const float *c1w, *c1b, *c2w, *c2b, *n1w, *n1b, *n2w, *n2b, *cscale;
    float *fa, *fb, *ca, *cb2, *HIa, *HJa;
    unsigned short *e2f, *c1f;
    int *nbr;
    float *dout;
};

__global__ __launch_bounds__(256, 4) void egnn_mega(MegaArgs A) {
    cg::grid_group grid = cg::this_grid();
    __shared__ __align__(16) SharedMem S;
    const int blk = blockIdx.x;            // 1024 blocks, 4 nodes each
    const int t = threadIdx.x;
    const int lane = t & 63, wid = t >> 6;

    // ---------- phase A: B-frags + embed + layer-0 HI/HJ + knn-0 ----------
    {
        const int TOT_E2 = LL * 5120;
        const int TOT = TOT_E2 + LL * 4096;
        const int u = blk * 256 + t;
        if (u < TOT) {
            if (u < TOT_E2) {
                int l = u / 5120, v = u - l * 5120;
                int jj = v & 7, la = (v >> 3) & 63, nt = (v >> 9) & 1, c = v >> 10;
                int n = nt * 16 + (la & 15);
                float val;
                if (c < 4) {
                    int k = 32 * c + (la >> 4) * 8 + jj;
                    val = A.e2w[(size_t)l * EH * DD + k * DD + n];
                } else {
                    int ks = (la >> 4) * 8 + jj;
                    val = (ks == 0) ? A.e2w[((size_t)l * EH + 128) * DD + n]
                        : (ks == 1) ? A.e2w[((size_t)l * EH + 129) * DD + n]
                        : (ks == 2) ? A.e2b[(size_t)l * DD + n] : 0.f;
                }
                A.e2f[u] = bf16_rne(val);
            } else {
                int v = u - TOT_E2;
                int jj = v & 7, la = (v >> 3) & 63, nt = (v >> 9) & 7, l = v >> 12;
                int k = (la >> 4) * 8 + jj;
                int n = nt * 16 + (la & 15);
                A.c1f[v] = bf16_rne(A.c1w[(size_t)l * DD * 128 + k * 128 + n]);
            }
        }
        // embed 4 nodes (stash in LDS via sx0 alias)
        float* sfe = S.sx0;   // [4][32]
        if (t < 128) {
            const int nl = t >> 5, o = t & 31;
            const int node = blk * 4 + nl;
            const float* f = A.feat + (size_t)node * DD;
            float a = A.embed_b[o];
#pragma unroll
            for (int k = 0; k < DD; k++) a = fmaf(f[k], A.embed_w[k * DD + o], a);
            a = lrelu(a);
            A.fa[(size_t)node * DD + o] = a;
            sfe[nl * DD + o] = a;
        }
        __syncthreads();
        // layer-0 HI/HJ for 4 nodes
        for (int idx = t; idx < 4 * EHP; idx += 256) {
            const int nl = idx / EHP, o = idx - nl * EHP;
            const size_t off = (size_t)(blk * 4 + nl) * EHP + o;
            if (o >= EH) { A.HIa[off] = 0.f; A.HJa[off] = 0.f; continue; }
            const float* fl = sfe + nl * DD;
            float aa = A.e1b[o], cc = 0.f;
#pragma unroll
            for (int k = 0; k < DD; k++) aa = fmaf(fl[k], A.e1w[k * EH + o], aa);
#pragma unroll
            for (int k = 0; k < DD; k++) cc = fmaf(fl[k], A.e1w[(DD + k) * EH + o], cc);
            A.HIa[off] = aa;
            A.HJa[off] = cc;
        }
        // knn-0: one node per wave
        {
            const int node = blk * 4 + wid;
            const int b = node >> 10, i = node & (NN - 1);
            unsigned* hist = (unsigned*)S.smA + wid * 256;
            knn_select((const float2*)A.coor + (size_t)b * NN, i, lane, hist,
                       A.nbr + (size_t)node * KK);
        }
    }
    grid.sync();

    // ---------- layers ----------
    const float* fin = A.fa;
    const float* cin = A.coor;
#pragma unroll 1
    for (int l = 0; l < LL; l++) {
        float* fo = (l == 0) ? A.fb : (l == 1) ? A.fa : A.dout;
        float* co = (l == 1) ? A.cb2 : A.ca;
        const float* w65  = A.e1w + ((size_t)l * 65 + 64) * EH;
        const unsigned short* e2fl = A.e2f + (size_t)l * 5120;
        const unsigned short* c1fl = A.c1f + (size_t)l * 4096;
        const float* gw  = A.gate_w + (size_t)l * DD;
        const float* gb  = A.gate_b + l;
        const float* c1b = A.c1b + (size_t)l * 128;
        const float* c2w = A.c2w + (size_t)l * 128;
        const float* c2b = A.c2b + l;
        const float* n1w = A.n1w + (size_t)l * 64 * 64;
        const float* n1b = A.n1b + (size_t)l * 64;
        const float* n2w = A.n2w + (size_t)l * 64 * 32;
        const float* n2b = A.n2b + (size_t)l * DD;
        const float* sc  = A.cscale + l;

#pragma unroll 1
        for (int nn = 0; nn < 4; nn++)
            layer_body(S, blk * 4 + nn, fin, cin, A.nbr, A.HIa, A.HJa, w65, e2fl, c1fl,
                       gw, gb, c1b, c2w, c2b, n1w, n1b, n2w, n2b, sc, fo, co);
        grid.sync();

        if (l < LL - 1) {
            // knn for next layer on new coords: one node per wave
            {
                const int node = blk * 4 + wid;
                const int b = node >> 10, i = node & (NN - 1);
                unsigned* hist = (unsigned*)S.smA + wid * 256;
                knn_select((const float2*)co + (size_t)b * NN, i, lane, hist,
                           A.nbr + (size_t)node * KK);
            }
            // next layer's HI/HJ for this block's 4 nodes
            const float* e1wn = A.e1w + (size_t)(l + 1) * 65 * EH;
            const float* e1bn = A.e1b + (size_t)(l + 1) * EH;
            for (int idx = t; idx < 4 * EHP; idx += 256) {
                const int nl = idx / EHP, o = idx - nl * EHP;
                const size_t off = (size_t)(blk * 4 + nl) * EHP + o;
                if (o >= EH) { A.HIa[off] = 0.f; A.HJa[off] = 0.f; continue; }
                const float* f = fo + (size_t)(blk * 4 + nl) * DD;
                float aa = e1bn[o], cc = 0.f;
#pragma unroll
                for (int k = 0; k < DD; k++) aa = fmaf(f[k], e1wn[k * EH + o], aa);
#pragma unroll
                for (int k = 0; k < DD; k++) cc = fmaf(f[k], e1wn[(DD + k) * EH + o], cc);
                A.HIa[off] = aa;
                A.HJa[off] = cc;
            }
            grid.sync();
        }
        fin = fo;
        cin = co;
    }
}

// =========================== fallback path (R4, verified) ===========================
__global__ __launch_bounds__(128) void prep_kernel(
    const float* __restrict__ feat, const float* __restrict__ coor,
    const float* __restrict__ ew, const float* __restrict__ eb,
    float* __restrict__ fout,
    const float* __restrict__ e1w0, const float* __restrict__ e1b0,
    float* __restrict__ HI, float* __restrict__ HJ,
    int* __restrict__ nbr,
    const float* __restrict__ e2w, const float* __restrict__ e2b,
    const float* __restrict__ c1w,
    unsigned short* __restrict__ e2f, unsigned short* __restrict__ c1f) {
    const int bid = blockIdx.x;
    const int t = threadIdx.x;
    __shared__ __align__(16) unsigned shist[2][256];
    if (bid < 2048) {
        __shared__ float sfe[2][DD];
        const int n0 = bid * 2;
        if (t < 64) {
            const int nl = t >> 5, o = t & 31;
            const float* f = feat + (size_t)(n0 + nl) * DD;
            float a = eb[o];
#pragma unroll
            for (int k = 0; k < DD; k++) a = fmaf(f[k], ew[k * DD + o], a);
            a = lrelu(a);
            fout[(size_t)(n0 + nl) * DD + o] = a;
            sfe[nl][o] = a;
        }
        __syncthreads();
        for (int idx = t; idx < 2 * EHP; idx += 128) {
            const int nl = idx / EHP, o = idx - nl * EHP;
            const size_t off = (size_t)(n0 + nl) * EHP + o;
            if (o >= EH) { HI[off] = 0.f; HJ[off] = 0.f; continue; }
            const float* fl = sfe[nl];
            float aa = e1b0[o], cc = 0.f;
#pragma unroll
            for (int k = 0; k < DD; k++) aa = fmaf(fl[k], e1w0[k * EH + o], aa);
#pragma unroll
            for (int k = 0; k < DD; k++) cc = fmaf(fl[k], e1w0[(DD + k) * EH + o], cc);
            HI[off] = aa;
            HJ[off] = cc;
        }
    } else if (bid < 4096) {
        const int node = (bid - 2048) * 2 + (t >> 6);
        const int b = node >> 10, i = node & (NN - 1);
        knn_select((const float2*)coor + (size_t)b * NN, i, t & 63, shist[t >> 6],
                   nbr + (size_t)node * KK);
    } else {
        const int TOT_E2 = LL * 5120;
        const int TOT = TOT_E2 + LL * 4096;
        for (int u = (bid - 4096) * 128 + t; u < TOT; u += 96 * 128) {
            if (u < TOT_E2) {
                int l = u / 5120, v = u - l * 5120;
                int jj = v & 7, la = (v >> 3) & 63, nt = (v >> 9) & 1, c = v >> 10;
                int n = nt * 16 + (la & 15);
                float val;
                if (c < 4) {
                    int k = 32 * c + (la >> 4) * 8 + jj;
                    val = e2w[(size_t)l * EH * DD + k * DD + n];
                } else {
                    int ks = (la >> 4) * 8 + jj;
                    val = (ks == 0) ? e2w[((size_t)l * EH + 128) * DD + n]
                        : (ks == 1) ? e2w[((size_t)l * EH + 129) * DD + n]
                        : (ks == 2) ? e2b[(size_t)l * DD + n] : 0.f;
                }
                e2f[u] = bf16_rne(val);
            } else {
                int v = u - TOT_E2;
                int jj = v & 7, la = (v >> 3) & 63, nt = (v >> 9) & 7, l = v >> 12;
                int k = (la >> 4) * 8 + jj;
                int n = nt * 16 + (la & 15);
                c1f[v] = bf16_rne(c1w[(size_t)l * DD * 128 + k * 128 + n]);
            }
        }
    }
}

__global__ __launch_bounds__(256) void knnpre_kernel(
    const float* __restrict__ coors, int* __restrict__ nbr,
    const float* __restrict__ feats, const float* __restrict__ e1w, const float* __restrict__ e1b,
    float* __restrict__ HI, float* __restrict__ HJ) {
    __shared__ __align__(16) unsigned shist[4][256];
    const int KNNB = BB * NN / 4;
    if (blockIdx.x >= KNNB) {
        int t = (int)(blockIdx.x - KNNB) * 256 + threadIdx.x;
        if (t >= BB * NN * EHP) return;
        int n = t / EHP, o = t % EHP;
        if (o >= EH) { HI[t] = 0.f; HJ[t] = 0.f; return; }
        const float* f = feats + n * DD;
        float a = e1b[o], c = 0.f;
#pragma unroll
        for (int k = 0; k < DD; k++) a = fmaf(f[k], e1w[k * EH + o], a);
#pragma unroll
        for (int k = 0; k < DD; k++) c = fmaf(f[k], e1w[(DD + k) * EH + o], c);
        HI[t] = a;
        HJ[t] = c;
        return;
    }
    const int node = (int)blockIdx.x * 4 + (threadIdx.x >> 6);
    const int b = node >> 10, i = node & (NN - 1);
    knn_select((const float2*)coors + (size_t)b * NN, i, threadIdx.x & 63,
               shist[threadIdx.x >> 6], nbr + (size_t)node * KK);
}

__global__ __launch_bounds__(256) void layer_kernel(
    const float* __restrict__ feats_in, const float* __restrict__ coors_in,
    const int*   __restrict__ nbr,
    const float* __restrict__ HI, const float* __restrict__ HJ,
    const float* __restrict__ w65,
    const unsigned short* __restrict__ e2f,
    const unsigned short* __restrict__ c1f,
    const float* __restrict__ gw, const float* __restrict__ gb,
    const float* __restrict__ c1b, const float* __restrict__ c2w, const float* __restrict__ c2b,
    const float* __restrict__ n1w, const float* __restrict__ n1b,
    const float* __restrict__ n2w, const float* __restrict__ n2b,
    const float* __restrict__ scale,
    float* __restrict__ feats_out, float* __restrict__ coors_out) {
    __shared__ __align__(16) SharedMem S;
    layer_body(S, blockIdx.x, feats_in, coors_in, nbr, HI, HJ, w65, e2f, c1f,
               gw, gb, c1b, c2w, c2b, n1w, n1b, n2w, n2b, scale, feats_out, coors_out);
}

extern "C" void kernel_launch(void* const* d_in, const int* in_sizes, int n_in,
                              void* d_out, int out_size, void* d_ws, size_t ws_size,
                              hipStream_t stream) {
    const float* feat_   = (const float*)d_in[0];
    const float* coor_   = (const float*)d_in[1];
    // d_in[2] = batch (int32, unused: equal-size graphs)
    const float* embed_w = (const float*)d_in[3];
    const float* embed_b = (const float*)d_in[4];
    const float* e1_w    = (const float*)d_in[5];
    const float* e1_b    = (const float*)d_in[6];
    const float* e2_w    = (const float*)d_in[7];
    const float* e2_b    = (const float*)d_in[8];
    const float* gate_w  = (const float*)d_in[9];
    const float* gate_b  = (const float*)d_in[10];
    const float* c1_w    = (const float*)d_in[11];
    const float* c1_b    = (const float*)d_in[12];
    const float* c2_w    = (const float*)d_in[13];
    const float* c2_b    = (const float*)d_in[14];
    const float* n1_w    = (const float*)d_in[15];
    const float* n1_b    = (const float*)d_in[16];
    const float* n2_w    = (const float*)d_in[17];
    const float* n2_b    = (const float*)d_in[18];
    const float* cscale  = (const float*)d_in[19];

    float* ws = (float*)d_ws;
    float* fa   = ws;   ws += BB * NN * DD;
    float* fb   = ws;   ws += BB * NN * DD;
    float* ca   = ws;   ws += BB * NN * 2;
    float* cb2  = ws;   ws += BB * NN * 2;
    float* HIa  = ws;   ws += BB * NN * EHP;
    float* HJa  = ws;   ws += BB * NN * EHP;
    unsigned short* e2f = (unsigned short*)ws;      // LL*5120 ushorts (5 K-chunks/layer)
    unsigned short* c1f = e2f + LL * 5120;          // LL*4096 ushorts
    int* nbr = (int*)(c1f + LL * 4096);

    MegaArgs ma;
    ma.feat = feat_; ma.coor = coor_;
    ma.embed_w = embed_w; ma.embed_b = embed_b;
    ma.e1w = e1_w; ma.e1b = e1_b; ma.e2w = e2_w; ma.e2b = e2_b;
    ma.gate_w = gate_w; ma.gate_b = gate_b;
    ma.c1w = c1_w; ma.c1b = c1_b; ma.c2w = c2_w; ma.c2b = c2_b;
    ma.n1w = n1_w; ma.n1b = n1_b; ma.n2w = n2_w; ma.n2b = n2_b; ma.cscale = cscale;
    ma.fa = fa; ma.fb = fb; ma.ca = ca; ma.cb2 = cb2; ma.HIa = HIa; ma.HJa = HJa;
    ma.e2f = e2f; ma.c1f = c1f; ma.nbr = nbr; ma.dout = (float*)d_out;
    void* kp[] = {&ma};

    hipError_t err = hipLaunchCooperativeKernel((void*)egnn_mega, dim3(BB * NN / 4),
                                                dim3(256), kp, 0, stream);
    if (err == hipSuccess) return;
    (void)hipGetLastError();   // clear; fall back to verified multi-launch path

    prep_kernel<<<4096 + 96, 128, 0, stream>>>(feat_, coor_, embed_w, embed_b, fa,
                                               e1_w, e1_b, HIa, HJa, nbr,
                                               e2_w, e2_b, c1_w, e2f, c1f);
    const int KNNB = BB * NN / 4;
    const int PREB = (BB * NN * EHP + 255) / 256;
    const float* fin = fa;
    const float* cin = coor_;
    float* fouts[LL] = {fb, fa, (float*)d_out};
    float* couts[LL] = {ca, cb2, ca};
    for (int l = 0; l < LL; l++) {
        if (l > 0)
            knnpre_kernel<<<KNNB + PREB, 256, 0, stream>>>(
                cin, nbr, fin, e1_w + (size_t)l * 65 * EH, e1_b + (size_t)l * EH, HIa, HJa);
        layer_kernel<<<BB * NN, 256, 0, stream>>>(
            fin, cin, nbr, HIa, HJa,
            e1_w + ((size_t)l * 65 + 64) * EH,
            e2f + (size_t)l * 5120,
            c1f + (size_t)l * 4096,
            gate_w + (size_t)l * DD,
            gate_b + l,
            c1_b + (size_t)l * 128,
            c2_w + (size_t)l * 128,
            c2_b + l,
            n1_w + (size_t)l * 64 * 64,
            n1_b + (size_t)l * 64,
            n2_w + (size_t)l * 64 * 32,
            n2_b + (size_t)l * DD,
            cscale + l,
            fouts[l], couts[l]);
        fin = fouts[l];
        cin = couts[l];
    }
}

// Round 6
// 328.679 us; speedup vs baseline: 4.7931x; 4.7931x over previous
//
#include <hip/hip_runtime.h>
#include <hip/hip_bf16.h>
#include <math.h>

#define BB 4
#define NN 1024
#define KK 128
#define DD 32
#define LL 3
#define EH 130
#define EHP 132

typedef float f32x4 __attribute__((ext_vector_type(4)));
typedef short s16x8 __attribute__((ext_vector_type(8)));

__device__ __forceinline__ float lrelu(float x) { return fmaxf(x, 0.1f * x); }

__device__ __forceinline__ unsigned pk2(float a, float b) {   // v_cvt_pk_bf16_f32 (RNE)
    __hip_bfloat162 h = __float22bfloat162_rn(float2{a, b});
    return *(unsigned*)&h;
}
__device__ __forceinline__ unsigned short bf16_hu(float v) {
    return (unsigned short)((__float_as_uint(v) + 0x8000u) >> 16);
}
__device__ __forceinline__ unsigned short bf16_rne(float v) {
    unsigned u = __float_as_uint(v);
    return (unsigned short)((u + 0x7fffu + ((u >> 16) & 1u)) >> 16);
}

// ---- exact wave-level KNN select for one node (4-pass LDS radix select; R4-verified) ----
__device__ __forceinline__ void knn_select(const float2* __restrict__ cbp, int i, int lane,
                                           unsigned* __restrict__ hist,   // per-wave 256 uints (LDS)
                                           int* __restrict__ nb) {
    const float2 ci = cbp[i];
    unsigned k[16];
#pragma unroll
    for (int s = 0; s < 16; s++) {
        float2 cj = cbp[lane + 64 * s];
        float dx = ci.x - cj.x, dy = ci.y - cj.y;
        float d = __fadd_rn(__fmul_rn(dx, dx), __fmul_rn(dy, dy));
        k[s] = __float_as_uint(d);
    }
    unsigned prefix = 0u;
    unsigned r = KK - 1;
#pragma unroll
    for (int pass = 0; pass < 4; pass++) {
        const int sh = 24 - 8 * pass;
        const unsigned mpref = (pass == 0) ? 0u : (0xFFFFFFFFu << (sh + 8));
        ((uint4*)hist)[lane] = uint4{0u, 0u, 0u, 0u};
        __threadfence_block();
#pragma unroll
        for (int s = 0; s < 16; s++) {
            if ((k[s] & mpref) == prefix)
                atomicAdd(&hist[(k[s] >> sh) & 255u], 1u);
        }
        __threadfence_block();
        const uint4 h = ((const uint4*)hist)[lane];
        const unsigned partial = h.x + h.y + h.z + h.w;
        unsigned incl = partial;
#pragma unroll
        for (int off = 1; off < 64; off <<= 1) {
            unsigned v = __shfl_up(incl, off, 64);
            if (lane >= off) incl += v;
        }
        const unsigned excl = incl - partial;
        const bool own = (r >= excl) && (r < incl);
        unsigned enc = 0u;
        if (own) {
            unsigned hh[4] = {h.x, h.y, h.z, h.w};
            unsigned e = excl;
            int bin = -1;
#pragma unroll
            for (int ii = 0; ii < 4; ii++) {
                if (bin < 0) {
                    if (r < e + hh[ii]) bin = ii;
                    else e += hh[ii];
                }
            }
            enc = (((unsigned)(4 * lane + bin)) << 16) | (r - e);
        }
        const unsigned long long mk = __ballot(own);
        const int src = __ffsll((unsigned long long)mk) - 1;
        enc = __shfl(enc, src, 64);
        prefix |= (enc >> 16) << sh;
        r = enc & 0xFFFFu;
    }
    const unsigned dstar = prefix;

    const unsigned long long below = (1ull << lane) - 1ull;
    unsigned run = 0;
#pragma unroll
    for (int s = 0; s < 16; s++) {
        unsigned long long m = __ballot(k[s] < dstar);
        if (k[s] < dstar) nb[run + (unsigned)__popcll(m & below)] = lane + 64 * s;
        run += (unsigned)__popcll(m);
    }
    const int need = KK - (int)run;   // >= 1
    unsigned tie = 0;
    for (int s = 0; s < 16 && (int)tie < need; s++) {
        unsigned long long m = __ballot(k[s] == dstar);
        if (k[s] == dstar) {
            unsigned r2 = tie + (unsigned)__popcll(m & below);
            if ((int)r2 < need) nb[run + r2] = lane + 64 * s;
        }
        tie += (unsigned)__popcll(m);
    }
}

// ---- prep: [0,2048) embed 2 nodes + layer-0 HI/HJ ; [2048,2144) B-frags ----
__global__ __launch_bounds__(128) void prep_kernel(
    const float* __restrict__ feat,
    const float* __restrict__ ew, const float* __restrict__ eb,
    float* __restrict__ fout,
    const float* __restrict__ e1w0, const float* __restrict__ e1b0,
    float* __restrict__ HI, float* __restrict__ HJ,
    const float* __restrict__ e2w, const float* __restrict__ e2b,
    const float* __restrict__ c1w,
    unsigned short* __restrict__ e2f, unsigned short* __restrict__ c1f) {
    const int bid = blockIdx.x;
    const int t = threadIdx.x;
    if (bid < 2048) {
        __shared__ float sfe[2][DD];
        const int n0 = bid * 2;
        if (t < 64) {
            const int nl = t >> 5, o = t & 31;
            const float* f = feat + (size_t)(n0 + nl) * DD;
            float a = eb[o];
#pragma unroll
            for (int k = 0; k < DD; k++) a = fmaf(f[k], ew[k * DD + o], a);
            a = lrelu(a);
            fout[(size_t)(n0 + nl) * DD + o] = a;
            sfe[nl][o] = a;
        }
        __syncthreads();
        for (int idx = t; idx < 2 * EHP; idx += 128) {
            const int nl = idx / EHP, o = idx - nl * EHP;
            const size_t off = (size_t)(n0 + nl) * EHP + o;
            if (o >= EH) { HI[off] = 0.f; HJ[off] = 0.f; continue; }
            const float* fl = sfe[nl];
            float aa = e1b0[o], cc = 0.f;
#pragma unroll
            for (int k = 0; k < DD; k++) aa = fmaf(fl[k], e1w0[k * EH + o], aa);
#pragma unroll
            for (int k = 0; k < DD; k++) cc = fmaf(fl[k], e1w0[(DD + k) * EH + o], cc);
            HI[off] = aa;
            HJ[off] = cc;
        }
    } else {
        // MFMA B-fragment precompute (bf16, fragment-ordered)
        const int TOT_E2 = LL * 5120;
        const int TOT = TOT_E2 + LL * 4096;
        for (int u = (bid - 2048) * 128 + t; u < TOT; u += 96 * 128) {
            if (u < TOT_E2) {
                int l = u / 5120, v = u - l * 5120;
                int jj = v & 7, la = (v >> 3) & 63, nt = (v >> 9) & 1, c = v >> 10;
                int n = nt * 16 + (la & 15);
                float val;
                if (c < 4) {
                    int k = 32 * c + (la >> 4) * 8 + jj;
                    val = e2w[(size_t)l * EH * DD + k * DD + n];
                } else {
                    int ks = (la >> 4) * 8 + jj;
                    val = (ks == 0) ? e2w[((size_t)l * EH + 128) * DD + n]
                        : (ks == 1) ? e2w[((size_t)l * EH + 129) * DD + n]
                        : (ks == 2) ? e2b[(size_t)l * DD + n] : 0.f;
                }
                e2f[u] = bf16_rne(val);
            } else {
                int v = u - TOT_E2;
                int jj = v & 7, la = (v >> 3) & 63, nt = (v >> 9) & 7, l = v >> 12;
                int k = (la >> 4) * 8 + jj;
                int n = nt * 16 + (la & 15);
                c1f[v] = bf16_rne(c1w[(size_t)l * DD * 128 + k * 128 + n]);
            }
        }
    }
}

// ---- fused layer: wave-0 radix KNN (in-LDS) + MFMA e2/c1 + reductions + node MLP
//      + next-layer HI/HJ tail (double-buffered) ----
__global__ __launch_bounds__(256) void layer_kernel(
    const float* __restrict__ feats_in, const float* __restrict__ coors_in,
    const float* __restrict__ HI, const float* __restrict__ HJ,
    const float* __restrict__ w65,
    const unsigned short* __restrict__ e2f,
    const unsigned short* __restrict__ c1f,
    const float* __restrict__ gw, const float* __restrict__ gb,
    const float* __restrict__ c1b, const float* __restrict__ c2w, const float* __restrict__ c2b,
    const float* __restrict__ n1w, const float* __restrict__ n1b,
    const float* __restrict__ n2w, const float* __restrict__ n2b,
    const float* __restrict__ scale,
    const float* __restrict__ e1wn, const float* __restrict__ e1bn,   // next-layer edge MLP (null on last)
    float* __restrict__ HIn, float* __restrict__ HJn,                 // next-layer HI/HJ buffers
    float* __restrict__ feats_out, float* __restrict__ coors_out) {
    const int node = blockIdx.x;
    const int b = node >> 10;
    const int t = threadIdx.x;
    const int lane = t & 63, wid = t >> 6;     // 4 waves
    const int ln = lane & 15, q = lane >> 4;
    const int rowbase = wid * 32;              // each wave owns 32 neighbor rows

    __shared__ __align__(16) float shi[EHP];
    __shared__ __align__(16) float sw65[EHP];
    __shared__ __align__(16) unsigned short smA[4 * 32 * 32];
    __shared__ float sx0[128], sx1[128], su[128], sv[128], srd[128];
    __shared__ int snb[128];
    __shared__ float sgw[DD], sfi[DD], sfo[DD];
    __shared__ float sc1b[128], sc2w[128];
    __shared__ float redm[4][DD], redc[4][2];
    __shared__ float sni[2 * DD], shd[2 * DD];
    __shared__ float sp1[4][2 * DD], sp2[4][DD];

    // wave 0: radix KNN for this node (hist in smA region; writes snb);
    // waves 1-3: stage LDS constants meanwhile
    if (t < 64) {
        knn_select((const float2*)coors_in + (size_t)b * NN, node & (NN - 1), lane,
                   (unsigned*)smA, snb);
    } else {
        for (int u = t - 64; u < EHP; u += 192) {
            shi[u] = HI[(size_t)node * EHP + u];
            sw65[u] = (u < EH) ? w65[u] : 0.f;
        }
        if (t - 64 < DD) { sfi[t - 64] = feats_in[node * DD + (t - 64)]; sgw[t - 64] = gw[t - 64]; }
        if (t >= 128) { sc1b[t - 128] = c1b[t - 128]; sc2w[t - 128] = c2w[t - 128]; }
    }
    __syncthreads();

    const float cix = coors_in[node * 2], ciy = coors_in[node * 2 + 1];
    if (t < 128) {
        const int j = snb[t];
        const float2 cj = *(const float2*)(coors_in + ((size_t)(b * NN) + j) * 2);
        const float dx = cix - cj.x, dy = ciy - cj.y;
        const float rd = __fadd_rn(__fmul_rn(dx, dx), __fmul_rn(dy, dy));
        srd[t] = rd;
        const float nrm = fmaxf(sqrtf(rd), 1e-8f);
        const float s = scale[0] / nrm;
        su[t] = dx * s;
        sv[t] = dy * s;
        const float2 hjt = *(const float2*)(HJ + ((size_t)(b * NN) + j) * EHP + 128);
        sx0[t] = lrelu(shi[128] + hjt.x + rd * sw65[128]);
        sx1[t] = lrelu(shi[129] + hjt.y + rd * sw65[129]);
    }
    __syncthreads();

    float rdR[2];
    const float* hjb[2];
#pragma unroll
    for (int mt = 0; mt < 2; mt++) {
        const int row = rowbase + mt * 16 + ln;
        rdR[mt] = srd[row];
        hjb[mt] = HJ + ((size_t)(b * NN) + snb[row]) * EHP;
    }

    const float4* shi4 = (const float4*)shi;
    const float4* sw4  = (const float4*)sw65;

    const f32x4 zz = {0.f, 0.f, 0.f, 0.f};
    f32x4 accA[2][2];
    accA[0][0] = zz; accA[0][1] = zz; accA[1][0] = zz; accA[1][1] = zz;

    float4 ha[2], hbv[2];
#pragma unroll
    for (int mt = 0; mt < 2; mt++) {
        const float4* hjp = (const float4*)(hjb[mt] + q * 8);
        ha[mt] = hjp[0];
        hbv[mt] = hjp[1];
    }
    s16x8 bcur0 = *(const s16x8*)(e2f + (0 * 64 + lane) * 8);
    s16x8 bcur1 = *(const s16x8*)(e2f + (1 * 64 + lane) * 8);

#pragma unroll 1
    for (int c = 0; c < 4; c++) {
        s16x8 bn0 = *(const s16x8*)(e2f + (((c + 1) * 2 + 0) * 64 + lane) * 8);
        s16x8 bn1 = *(const s16x8*)(e2f + (((c + 1) * 2 + 1) * 64 + lane) * 8);
        float4 nha[2], nhb[2];
        if (c < 3) {
#pragma unroll
            for (int mt = 0; mt < 2; mt++) {
                const float4* hjp = (const float4*)(hjb[mt] + (c + 1) * 32 + q * 8);
                nha[mt] = hjp[0];
                nhb[mt] = hjp[1];
            }
        }
        const int kb = c * 8 + q * 2;
        const float4 hi0 = shi4[kb], hi1 = shi4[kb + 1];
        const float4 wv0 = sw4[kb],  wv1 = sw4[kb + 1];
#pragma unroll
        for (int mt = 0; mt < 2; mt++) {
            const float r = rdR[mt];
            union { s16x8 v; unsigned u[4]; } A;
            A.u[0] = pk2(lrelu(hi0.x + ha[mt].x + r * wv0.x), lrelu(hi0.y + ha[mt].y + r * wv0.y));
            A.u[1] = pk2(lrelu(hi0.z + ha[mt].z + r * wv0.z), lrelu(hi0.w + ha[mt].w + r * wv0.w));
            A.u[2] = pk2(lrelu(hi1.x + hbv[mt].x + r * wv1.x), lrelu(hi1.y + hbv[mt].y + r * wv1.y));
            A.u[3] = pk2(lrelu(hi1.z + hbv[mt].z + r * wv1.z), lrelu(hi1.w + hbv[mt].w + r * wv1.w));
            accA[mt][0] = __builtin_amdgcn_mfma_f32_16x16x32_bf16(A.v, bcur0, accA[mt][0], 0, 0, 0);
            accA[mt][1] = __builtin_amdgcn_mfma_f32_16x16x32_bf16(A.v, bcur1, accA[mt][1], 0, 0, 0);
        }
#pragma unroll
        for (int mt = 0; mt < 2; mt++) { ha[mt] = nha[mt]; hbv[mt] = nhb[mt]; }
        bcur0 = bn0; bcur1 = bn1;
    }

    // chunk 4: k-slot0 = x128, k-slot1 = x129, k-slot2 = 1.0 (bias row)
    {
#pragma unroll
        for (int mt = 0; mt < 2; mt++) {
            const int row = rowbase + mt * 16 + ln;
            union { s16x8 v; unsigned u[4]; } A;
            const unsigned p0 = pk2(sx0[row], sx1[row]);
            A.u[0] = (q == 0) ? p0 : 0u;
            A.u[1] = (q == 0) ? 0x00003f80u : 0u;   // bf16(1.0) in low half
            A.u[2] = 0u;
            A.u[3] = 0u;
            accA[mt][0] = __builtin_amdgcn_mfma_f32_16x16x32_bf16(A.v, bcur0, accA[mt][0], 0, 0, 0);
            accA[mt][1] = __builtin_amdgcn_mfma_f32_16x16x32_bf16(A.v, bcur1, accA[mt][1], 0, 0, 0);
        }
    }

    // preload all 8 c1 B-frags; gate + smA phases cover the latency
    s16x8 cfr[8];
#pragma unroll
    for (int g8 = 0; g8 < 8; g8++)
        cfr[g8] = *(const s16x8*)(c1f + (g8 * 64 + lane) * 8);

#pragma unroll
    for (int mt = 0; mt < 2; mt++)
#pragma unroll
        for (int nt = 0; nt < 2; nt++)
#pragma unroll
            for (int r = 0; r < 4; r++)
                accA[mt][nt][r] = lrelu(accA[mt][nt][r]);

    const float gbv = gb[0];
#pragma unroll
    for (int mt = 0; mt < 2; mt++) {
        float p[4];
#pragma unroll
        for (int r = 0; r < 4; r++)
            p[r] = accA[mt][0][r] * sgw[ln] + accA[mt][1][r] * sgw[16 + ln];
#pragma unroll
        for (int off = 1; off <= 8; off <<= 1)
#pragma unroll
            for (int r = 0; r < 4; r++) p[r] += __shfl_xor(p[r], off);
#pragma unroll
        for (int r = 0; r < 4; r++) {
            const float g = 1.f / (1.f + __expf(-(p[r] + gbv)));
            accA[mt][0][r] *= g;
            accA[mt][1][r] *= g;
        }
    }

    float mi0 = 0.f, mi1 = 0.f;
#pragma unroll
    for (int mt = 0; mt < 2; mt++)
#pragma unroll
        for (int r = 0; r < 4; r++) { mi0 += accA[mt][0][r]; mi1 += accA[mt][1][r]; }
    mi0 += __shfl_xor(mi0, 16); mi0 += __shfl_xor(mi0, 32);
    mi1 += __shfl_xor(mi1, 16); mi1 += __shfl_xor(mi1, 32);
    if (lane < 16) { redm[wid][lane] = mi0; redm[wid][16 + lane] = mi1; }

    __syncthreads();   // smA was used as knn hist; ensure all waves past it (also orders reuse)
    unsigned short* smw = smA + wid * (32 * 32);
#pragma unroll
    for (int mt = 0; mt < 2; mt++)
#pragma unroll
        for (int nt = 0; nt < 2; nt++)
#pragma unroll
            for (int r = 0; r < 4; r++) {
                const int prow = (r << 3) | (4 * mt + q);
                smw[prow * 32 + nt * 16 + ln] = bf16_hu(accA[mt][nt][r]);
            }

    s16x8 a4[2];
#pragma unroll
    for (int mt = 0; mt < 2; mt++) {
        const int prow = ((ln & 3) << 3) | (4 * mt + (ln >> 2));
        a4[mt] = *(const s16x8*)(smw + prow * 32 + q * 8);
    }

    float cacc[2][4];
#pragma unroll
    for (int mt = 0; mt < 2; mt++)
#pragma unroll
        for (int r = 0; r < 4; r++) cacc[mt][r] = 0.f;

#pragma unroll
    for (int g = 0; g < 4; g++) {
        const float cb0 = sc1b[(2 * g + 0) * 16 + ln];
        const float cb1 = sc1b[(2 * g + 1) * 16 + ln];
        const f32x4 ci0 = {cb0, cb0, cb0, cb0};
        const f32x4 ci1 = {cb1, cb1, cb1, cb1};
        f32x4 c20[2], c21[2];
#pragma unroll
        for (int mt = 0; mt < 2; mt++) {
            c20[mt] = __builtin_amdgcn_mfma_f32_16x16x32_bf16(a4[mt], cfr[2 * g + 0], ci0, 0, 0, 0);
            c21[mt] = __builtin_amdgcn_mfma_f32_16x16x32_bf16(a4[mt], cfr[2 * g + 1], ci1, 0, 0, 0);
        }
#pragma unroll
        for (int h = 0; h < 2; h++) {
            const float c2wv = sc2w[(2 * g + h) * 16 + ln];
#pragma unroll
            for (int mt = 0; mt < 2; mt++)
#pragma unroll
                for (int r = 0; r < 4; r++) {
                    const float v = (h ? c21[mt][r] : c20[mt][r]);
                    cacc[mt][r] = fmaf(lrelu(v), c2wv, cacc[mt][r]);
                }
        }
    }
#pragma unroll
    for (int off = 1; off <= 8; off <<= 1)
#pragma unroll
        for (int mt = 0; mt < 2; mt++)
#pragma unroll
            for (int r = 0; r < 4; r++) cacc[mt][r] += __shfl_xor(cacc[mt][r], off);

    const float c2bv = c2b[0];
    float vxp = 0.f, vyp = 0.f;
    if (ln == 0) {
#pragma unroll
        for (int mt = 0; mt < 2; mt++)
#pragma unroll
            for (int r = 0; r < 4; r++) {
                const int row = rowbase + mt * 16 + q * 4 + r;
                const float cw = cacc[mt][r] + c2bv;
                vxp = fmaf(cw, su[row], vxp);
                vyp = fmaf(cw, sv[row], vyp);
            }
    }
    vxp += __shfl_xor(vxp, 16); vxp += __shfl_xor(vxp, 32);
    vyp += __shfl_xor(vyp, 16); vyp += __shfl_xor(vyp, 32);
    if (lane == 0) { redc[wid][0] = vxp; redc[wid][1] = vyp; }

    __syncthreads();
    if (t < DD) {
        sni[t] = sfi[t];
        sni[DD + t] = redm[0][t] + redm[1][t] + redm[2][t] + redm[3][t];
    }
    __syncthreads();
    {   // n1: 4-way K-split over 256 threads (16-FMA chains)
        const int o = t & 63, p = t >> 6;
        float a = 0.f;
#pragma unroll
        for (int k = 0; k < 16; k++) a = fmaf(sni[p * 16 + k], n1w[(p * 16 + k) * 64 + o], a);
        sp1[p][o] = a;
    }
    __syncthreads();
    if (t < 2 * DD)
        shd[t] = lrelu(n1b[t] + ((sp1[0][t] + sp1[1][t]) + (sp1[2][t] + sp1[3][t])));
    __syncthreads();
    if (t < 128) {   // n2: 4-way K-split over 128 threads
        const int o = t & 31, p = t >> 5;
        float a = 0.f;
#pragma unroll
        for (int k = 0; k < 16; k++) a = fmaf(shd[p * 16 + k], n2w[(p * 16 + k) * DD + o], a);
        sp2[p][o] = a;
    }
    __syncthreads();
    if (t < DD) {
        const float val = n2b[t] + ((sp2[0][t] + sp2[1][t]) + (sp2[2][t] + sp2[3][t])) + sfi[t];
        feats_out[node * DD + t] = val;
        sfo[t] = val;
    }
    if (t == 0) {
        coors_out[node * 2]     = cix + redc[0][0] + redc[1][0] + redc[2][0] + redc[3][0];
        coors_out[node * 2 + 1] = ciy + redc[0][1] + redc[1][1] + redc[2][1] + redc[3][1];
    }
    __syncthreads();

    // tail: next layer's HI/HJ for this node (node-local; double-buffered so no race)
    if (e1wn) {
        for (int idx = t; idx < 2 * EHP; idx += 256) {
            const int nl = idx / EHP, o = idx - nl * EHP;
            float* dst = (nl ? HJn : HIn) + (size_t)node * EHP + o;
            if (o >= EH) { *dst = 0.f; continue; }
            const int rowoff = nl ? DD : 0;
            float a = nl ? 0.f : e1bn[o];
#pragma unroll
            for (int k = 0; k < DD; k++) a = fmaf(sfo[k], e1wn[(rowoff + k) * EH + o], a);
            *dst = a;
        }
    }
}

extern "C" void kernel_launch(void* const* d_in, const int* in_sizes, int n_in,
                              void* d_out, int out_size, void* d_ws, size_t ws_size,
                              hipStream_t stream) {
    const float* feat_   = (const float*)d_in[0];
    const float* coor_   = (const float*)d_in[1];
    // d_in[2] = batch (int32, unused: equal-size graphs)
    const float* embed_w = (const float*)d_in[3];
    const float* embed_b = (const float*)d_in[4];
    const float* e1_w    = (const float*)d_in[5];
    const float* e1_b    = (const float*)d_in[6];
    const float* e2_w    = (const float*)d_in[7];
    const float* e2_b    = (const float*)d_in[8];
    const float* gate_w  = (const float*)d_in[9];
    const float* gate_b  = (const float*)d_in[10];
    const float* c1_w    = (const float*)d_in[11];
    const float* c1_b    = (const float*)d_in[12];
    const float* c2_w    = (const float*)d_in[13];
    const float* c2_b    = (const float*)d_in[14];
    const float* n1_w    = (const float*)d_in[15];
    const float* n1_b    = (const float*)d_in[16];
    const float* n2_w    = (const float*)d_in[17];
    const float* n2_b    = (const float*)d_in[18];
    const float* cscale  = (const float*)d_in[19];

    float* ws = (float*)d_ws;
    float* fa   = ws;   ws += BB * NN * DD;
    float* fb   = ws;   ws += BB * NN * DD;
    float* ca   = ws;   ws += BB * NN * 2;
    float* cb2  = ws;   ws += BB * NN * 2;
    float* HI0  = ws;   ws += BB * NN * EHP;
    float* HJ0  = ws;   ws += BB * NN * EHP;
    float* HI1  = ws;   ws += BB * NN * EHP;
    float* HJ1  = ws;   ws += BB * NN * EHP;
    unsigned short* e2f = (unsigned short*)ws;      // LL*5120 ushorts (5 K-chunks/layer)
    unsigned short* c1f = e2f + LL * 5120;          // LL*4096 ushorts

    // launch 1: embed + layer-0 HI/HJ + B-frags (all node-local / independent)
    prep_kernel<<<2048 + 96, 128, 0, stream>>>(feat_, embed_w, embed_b, fa,
                                               e1_w, e1_b, HI0, HJ0,
                                               e2_w, e2_b, c1_w, e2f, c1f);

    float* HIbuf[2] = {HI0, HI1};
    float* HJbuf[2] = {HJ0, HJ1};
    const float* fin = fa;
    const float* cin = coor_;
    float* fouts[LL] = {fb, fa, (float*)d_out};
    float* couts[LL] = {ca, cb2, ca};

    for (int l = 0; l < LL; l++) {
        const int cur = l & 1, nxt = (l + 1) & 1;
        layer_kernel<<<BB * NN, 256, 0, stream>>>(
            fin, cin, HIbuf[cur], HJbuf[cur],
            e1_w + ((size_t)l * 65 + 64) * EH,
            e2f + (size_t)l * 5120,
            c1f + (size_t)l * 4096,
            gate_w + (size_t)l * DD,
            gate_b + l,
            c1_b + (size_t)l * 128,
            c2_w + (size_t)l * 128,
            c2_b + l,
            n1_w + (size_t)l * 64 * 64,
            n1_b + (size_t)l * 64,
            n2_w + (size_t)l * 64 * 32,
            n2_b + (size_t)l * DD,
            cscale + l,
            (l < LL - 1) ? (e1_w + (size_t)(l + 1) * 65 * EH) : nullptr,
            (l < LL - 1) ? (e1_b + (size_t)(l + 1) * EH) : nullptr,
            HIbuf[nxt], HJbuf[nxt],
            fouts[l], couts[l]);
        fin = fouts[l];
        cin = couts[l];
    }
}

// Round 7
// 316.774 us; speedup vs baseline: 4.9733x; 1.0376x over previous
//
#include <hip/hip_runtime.h>
#include <hip/hip_bf16.h>
#include <math.h>

#define BB 4
#define NN 1024
#define KK 128
#define DD 32
#define LL 3
#define EH 130
#define EHP 132

typedef float f32x4 __attribute__((ext_vector_type(4)));
typedef short s16x8 __attribute__((ext_vector_type(8)));

__device__ __forceinline__ float lrelu(float x) { return fmaxf(x, 0.1f * x); }

__device__ __forceinline__ unsigned pk2(float a, float b) {   // v_cvt_pk_bf16_f32 (RNE)
    __hip_bfloat162 h = __float22bfloat162_rn(float2{a, b});
    return *(unsigned*)&h;
}
__device__ __forceinline__ unsigned short bf16_hu(float v) {
    return (unsigned short)((__float_as_uint(v) + 0x8000u) >> 16);
}
__device__ __forceinline__ unsigned short bf16_rne(float v) {
    unsigned u = __float_as_uint(v);
    return (unsigned short)((u + 0x7fffu + ((u >> 16) & 1u)) >> 16);
}

// ---- exact BLOCK-cooperative KNN select (4 waves share the work) ----
// Wave w owns nodes [w*256, (w+1)*256): 4 distances/lane. 4-pass 8-bit radix select with
// per-wave 256-bin LDS histograms (no inter-wave atomic contention) + block scan.
// Extraction order = ascending node index (wave-major, then s, then lane) — identical
// semantics to the R4-verified per-wave version (strictly-less, then ties in index order).
__device__ __forceinline__ void knn_block(const float2* __restrict__ cbp, int i, int t,
                                          unsigned* __restrict__ hist,   // 4*256 uints (LDS)
                                          volatile unsigned* __restrict__ scr, // 16 uints (LDS)
                                          int* __restrict__ nb) {
    const int lane = t & 63, wid = t >> 6;
    unsigned* histw = hist + wid * 256;
    const float2 ci = cbp[i];
    unsigned k[4];
#pragma unroll
    for (int s = 0; s < 4; s++) {
        float2 cj = cbp[wid * 256 + s * 64 + lane];
        float dx = ci.x - cj.x, dy = ci.y - cj.y;
        // match numpy per-op rounding exactly (no fma contraction)
        float d = __fadd_rn(__fmul_rn(dx, dx), __fmul_rn(dy, dy));
        k[s] = __float_as_uint(d);
    }
    unsigned prefix = 0u;
    unsigned r = KK - 1;
#pragma unroll
    for (int pass = 0; pass < 4; pass++) {
        const int sh = 24 - 8 * pass;
        const unsigned mpref = (pass == 0) ? 0u : (0xFFFFFFFFu << (sh + 8));
        ((uint4*)histw)[lane] = uint4{0u, 0u, 0u, 0u};   // own-wave hist; in-order DS ops
#pragma unroll
        for (int s = 0; s < 4; s++) {
            if ((k[s] & mpref) == prefix)
                atomicAdd(&histw[(k[s] >> sh) & 255u], 1u);
        }
        __syncthreads();
        // bin t total across the 4 wave-histograms; block inclusive scan over 256 bins
        unsigned tot = hist[t] + hist[256 + t] + hist[512 + t] + hist[768 + t];
        unsigned incl = tot;
#pragma unroll
        for (int off = 1; off < 64; off <<= 1) {
            unsigned v = __shfl_up(incl, off, 64);
            if (lane >= off) incl += v;
        }
        if (lane == 63) scr[wid] = incl;
        __syncthreads();
        unsigned woff = 0;
#pragma unroll
        for (int w = 0; w < 4; w++)
            if (w < wid) woff += scr[w];
        incl += woff;
        const unsigned excl = incl - tot;
        if (r >= excl && r < incl) { scr[4] = (unsigned)t; scr[5] = r - excl; }  // unique owner
        __syncthreads();
        prefix |= scr[4] << sh;
        r = scr[5];
    }
    const unsigned dstar = prefix;

    const unsigned long long below = (1ull << lane) - 1ull;
    unsigned long long mL[4], mE[4];
    unsigned cntL = 0, cntE = 0;
#pragma unroll
    for (int s = 0; s < 4; s++) {
        mL[s] = __ballot(k[s] < dstar);
        mE[s] = __ballot(k[s] == dstar);
        cntL += (unsigned)__popcll(mL[s]);
        cntE += (unsigned)__popcll(mE[s]);
    }
    if (lane == 0) { scr[8 + wid] = cntL; scr[12 + wid] = cntE; }
    __syncthreads();
    unsigned offL = 0, offE = 0, totalL = 0;
#pragma unroll
    for (int w = 0; w < 4; w++) {
        unsigned cl = scr[8 + w];
        if (w < wid) { offL += cl; offE += scr[12 + w]; }
        totalL += cl;
    }
    unsigned run = offL;
#pragma unroll
    for (int s = 0; s < 4; s++) {
        if (k[s] < dstar) nb[run + (unsigned)__popcll(mL[s] & below)] = wid * 256 + s * 64 + lane;
        run += (unsigned)__popcll(mL[s]);
    }
    const int need = KK - (int)totalL;   // >= 1
    unsigned tie = offE;
#pragma unroll
    for (int s = 0; s < 4; s++) {
        if (k[s] == dstar) {
            unsigned r2 = tie + (unsigned)__popcll(mE[s] & below);
            if ((int)r2 < need) nb[totalL + r2] = wid * 256 + s * 64 + lane;
        }
        tie += (unsigned)__popcll(mE[s]);
    }
}

// ---- prep: [0,2048) embed 2 nodes + layer-0 HI/HJ ; [2048,2144) B-frags ----
__global__ __launch_bounds__(128) void prep_kernel(
    const float* __restrict__ feat,
    const float* __restrict__ ew, const float* __restrict__ eb,
    float* __restrict__ fout,
    const float* __restrict__ e1w0, const float* __restrict__ e1b0,
    float* __restrict__ HI, float* __restrict__ HJ,
    const float* __restrict__ e2w, const float* __restrict__ e2b,
    const float* __restrict__ c1w,
    unsigned short* __restrict__ e2f, unsigned short* __restrict__ c1f) {
    const int bid = blockIdx.x;
    const int t = threadIdx.x;
    if (bid < 2048) {
        __shared__ float sfe[2][DD];
        const int n0 = bid * 2;
        if (t < 64) {
            const int nl = t >> 5, o = t & 31;
            const float* f = feat + (size_t)(n0 + nl) * DD;
            float a = eb[o];
#pragma unroll
            for (int k = 0; k < DD; k++) a = fmaf(f[k], ew[k * DD + o], a);
            a = lrelu(a);
            fout[(size_t)(n0 + nl) * DD + o] = a;
            sfe[nl][o] = a;
        }
        __syncthreads();
        for (int idx = t; idx < 2 * EHP; idx += 128) {
            const int nl = idx / EHP, o = idx - nl * EHP;
            const size_t off = (size_t)(n0 + nl) * EHP + o;
            if (o >= EH) { HI[off] = 0.f; HJ[off] = 0.f; continue; }
            const float* fl = sfe[nl];
            float aa = e1b0[o], cc = 0.f;
#pragma unroll
            for (int k = 0; k < DD; k++) aa = fmaf(fl[k], e1w0[k * EH + o], aa);
#pragma unroll
            for (int k = 0; k < DD; k++) cc = fmaf(fl[k], e1w0[(DD + k) * EH + o], cc);
            HI[off] = aa;
            HJ[off] = cc;
        }
    } else {
        // MFMA B-fragment precompute (bf16, fragment-ordered)
        const int TOT_E2 = LL * 5120;
        const int TOT = TOT_E2 + LL * 4096;
        for (int u = (bid - 2048) * 128 + t; u < TOT; u += 96 * 128) {
            if (u < TOT_E2) {
                int l = u / 5120, v = u - l * 5120;
                int jj = v & 7, la = (v >> 3) & 63, nt = (v >> 9) & 1, c = v >> 10;
                int n = nt * 16 + (la & 15);
                float val;
                if (c < 4) {
                    int k = 32 * c + (la >> 4) * 8 + jj;
                    val = e2w[(size_t)l * EH * DD + k * DD + n];
                } else {
                    int ks = (la >> 4) * 8 + jj;
                    val = (ks == 0) ? e2w[((size_t)l * EH + 128) * DD + n]
                        : (ks == 1) ? e2w[((size_t)l * EH + 129) * DD + n]
                        : (ks == 2) ? e2b[(size_t)l * DD + n] : 0.f;
                }
                e2f[u] = bf16_rne(val);
            } else {
                int v = u - TOT_E2;
                int jj = v & 7, la = (v >> 3) & 63, nt = (v >> 9) & 7, l = v >> 12;
                int k = (la >> 4) * 8 + jj;
                int n = nt * 16 + (la & 15);
                c1f[v] = bf16_rne(c1w[(size_t)l * DD * 128 + k * 128 + n]);
            }
        }
    }
}

// ---- fused layer: block-cooperative radix KNN + MFMA e2/c1 + reductions + node MLP
//      + next-layer HI/HJ tail (double-buffered) ----
__global__ __launch_bounds__(256) void layer_kernel(
    const float* __restrict__ feats_in, const float* __restrict__ coors_in,
    const float* __restrict__ HI, const float* __restrict__ HJ,
    const float* __restrict__ w65,
    const unsigned short* __restrict__ e2f,
    const unsigned short* __restrict__ c1f,
    const float* __restrict__ gw, const float* __restrict__ gb,
    const float* __restrict__ c1b, const float* __restrict__ c2w, const float* __restrict__ c2b,
    const float* __restrict__ n1w, const float* __restrict__ n1b,
    const float* __restrict__ n2w, const float* __restrict__ n2b,
    const float* __restrict__ scale,
    const float* __restrict__ e1wn, const float* __restrict__ e1bn,   // next-layer edge MLP (null on last)
    float* __restrict__ HIn, float* __restrict__ HJn,                 // next-layer HI/HJ buffers
    float* __restrict__ feats_out, float* __restrict__ coors_out) {
    const int node = blockIdx.x;
    const int b = node >> 10;
    const int t = threadIdx.x;
    const int lane = t & 63, wid = t >> 6;     // 4 waves
    const int ln = lane & 15, q = lane >> 4;
    const int rowbase = wid * 32;              // each wave owns 32 neighbor rows

    __shared__ __align__(16) float shi[EHP];
    __shared__ __align__(16) float sw65[EHP];
    __shared__ __align__(16) unsigned short smA[4 * 32 * 32];   // also: 4KB knn hist
    __shared__ unsigned sknn[16];
    __shared__ float sx0[128], sx1[128], su[128], sv[128], srd[128];
    __shared__ int snb[128];
    __shared__ float sgw[DD], sfi[DD], sfo[DD];
    __shared__ float sc1b[128], sc2w[128];
    __shared__ float redm[4][DD], redc[4][2];
    __shared__ float sni[2 * DD], shd[2 * DD];
    __shared__ float sp1[4][2 * DD], sp2[4][DD];

    // stage LDS constants (cheap, all waves), then block-cooperative KNN
    for (int u = t; u < EHP; u += 256) {
        shi[u] = HI[(size_t)node * EHP + u];
        sw65[u] = (u < EH) ? w65[u] : 0.f;
    }
    if (t < DD) { sfi[t] = feats_in[node * DD + t]; sgw[t] = gw[t]; }
    if (t >= 128) { sc1b[t - 128] = c1b[t - 128]; sc2w[t - 128] = c2w[t - 128]; }

    knn_block((const float2*)coors_in + (size_t)b * NN, node & (NN - 1), t,
              (unsigned*)smA, sknn, snb);
    __syncthreads();

    const float cix = coors_in[node * 2], ciy = coors_in[node * 2 + 1];
    if (t < 128) {
        const int j = snb[t];
        const float2 cj = *(const float2*)(coors_in + ((size_t)(b * NN) + j) * 2);
        const float dx = cix - cj.x, dy = ciy - cj.y;
        const float rd = __fadd_rn(__fmul_rn(dx, dx), __fmul_rn(dy, dy));
        srd[t] = rd;
        const float nrm = fmaxf(sqrtf(rd), 1e-8f);
        const float s = scale[0] / nrm;
        su[t] = dx * s;
        sv[t] = dy * s;
        const float2 hjt = *(const float2*)(HJ + ((size_t)(b * NN) + j) * EHP + 128);
        sx0[t] = lrelu(shi[128] + hjt.x + rd * sw65[128]);
        sx1[t] = lrelu(shi[129] + hjt.y + rd * sw65[129]);
    }
    __syncthreads();

    float rdR[2];
    const float* hjb[2];
#pragma unroll
    for (int mt = 0; mt < 2; mt++) {
        const int row = rowbase + mt * 16 + ln;
        rdR[mt] = srd[row];
        hjb[mt] = HJ + ((size_t)(b * NN) + snb[row]) * EHP;
    }

    const float4* shi4 = (const float4*)shi;
    const float4* sw4  = (const float4*)sw65;

    const f32x4 zz = {0.f, 0.f, 0.f, 0.f};
    f32x4 accA[2][2];
    accA[0][0] = zz; accA[0][1] = zz; accA[1][0] = zz; accA[1][1] = zz;

    float4 ha[2], hbv[2];
#pragma unroll
    for (int mt = 0; mt < 2; mt++) {
        const float4* hjp = (const float4*)(hjb[mt] + q * 8);
        ha[mt] = hjp[0];
        hbv[mt] = hjp[1];
    }
    s16x8 bcur0 = *(const s16x8*)(e2f + (0 * 64 + lane) * 8);
    s16x8 bcur1 = *(const s16x8*)(e2f + (1 * 64 + lane) * 8);

#pragma unroll 1
    for (int c = 0; c < 4; c++) {
        s16x8 bn0 = *(const s16x8*)(e2f + (((c + 1) * 2 + 0) * 64 + lane) * 8);
        s16x8 bn1 = *(const s16x8*)(e2f + (((c + 1) * 2 + 1) * 64 + lane) * 8);
        float4 nha[2], nhb[2];
        if (c < 3) {
#pragma unroll
            for (int mt = 0; mt < 2; mt++) {
                const float4* hjp = (const float4*)(hjb[mt] + (c + 1) * 32 + q * 8);
                nha[mt] = hjp[0];
                nhb[mt] = hjp[1];
            }
        }
        const int kb = c * 8 + q * 2;
        const float4 hi0 = shi4[kb], hi1 = shi4[kb + 1];
        const float4 wv0 = sw4[kb],  wv1 = sw4[kb + 1];
#pragma unroll
        for (int mt = 0; mt < 2; mt++) {
            const float r = rdR[mt];
            union { s16x8 v; unsigned u[4]; } A;
            A.u[0] = pk2(lrelu(hi0.x + ha[mt].x + r * wv0.x), lrelu(hi0.y + ha[mt].y + r * wv0.y));
            A.u[1] = pk2(lrelu(hi0.z + ha[mt].z + r * wv0.z), lrelu(hi0.w + ha[mt].w + r * wv0.w));
            A.u[2] = pk2(lrelu(hi1.x + hbv[mt].x + r * wv1.x), lrelu(hi1.y + hbv[mt].y + r * wv1.y));
            A.u[3] = pk2(lrelu(hi1.z + hbv[mt].z + r * wv1.z), lrelu(hi1.w + hbv[mt].w + r * wv1.w));
            accA[mt][0] = __builtin_amdgcn_mfma_f32_16x16x32_bf16(A.v, bcur0, accA[mt][0], 0, 0, 0);
            accA[mt][1] = __builtin_amdgcn_mfma_f32_16x16x32_bf16(A.v, bcur1, accA[mt][1], 0, 0, 0);
        }
#pragma unroll
        for (int mt = 0; mt < 2; mt++) { ha[mt] = nha[mt]; hbv[mt] = nhb[mt]; }
        bcur0 = bn0; bcur1 = bn1;
    }

    // chunk 4: k-slot0 = x128, k-slot1 = x129, k-slot2 = 1.0 (bias row)
    {
#pragma unroll
        for (int mt = 0; mt < 2; mt++) {
            const int row = rowbase + mt * 16 + ln;
            union { s16x8 v; unsigned u[4]; } A;
            const unsigned p0 = pk2(sx0[row], sx1[row]);
            A.u[0] = (q == 0) ? p0 : 0u;
            A.u[1] = (q == 0) ? 0x00003f80u : 0u;   // bf16(1.0) in low half
            A.u[2] = 0u;
            A.u[3] = 0u;
            accA[mt][0] = __builtin_amdgcn_mfma_f32_16x16x32_bf16(A.v, bcur0, accA[mt][0], 0, 0, 0);
            accA[mt][1] = __builtin_amdgcn_mfma_f32_16x16x32_bf16(A.v, bcur1, accA[mt][1], 0, 0, 0);
        }
    }

    // preload all 8 c1 B-frags; gate phase covers the latency
    s16x8 cfr[8];
#pragma unroll
    for (int g8 = 0; g8 < 8; g8++)
        cfr[g8] = *(const s16x8*)(c1f + (g8 * 64 + lane) * 8);

#pragma unroll
    for (int mt = 0; mt < 2; mt++)
#pragma unroll
        for (int nt = 0; nt < 2; nt++)
#pragma unroll
            for (int r = 0; r < 4; r++)
                accA[mt][nt][r] = lrelu(accA[mt][nt][r]);

    const float gbv = gb[0];
#pragma unroll
    for (int mt = 0; mt < 2; mt++) {
        float p[4];
#pragma unroll
        for (int r = 0; r < 4; r++)
            p[r] = accA[mt][0][r] * sgw[ln] + accA[mt][1][r] * sgw[16 + ln];
#pragma unroll
        for (int off = 1; off <= 8; off <<= 1)
#pragma unroll
            for (int r = 0; r < 4; r++) p[r] += __shfl_xor(p[r], off);
#pragma unroll
        for (int r = 0; r < 4; r++) {
            const float g = 1.f / (1.f + __expf(-(p[r] + gbv)));
            accA[mt][0][r] *= g;
            accA[mt][1][r] *= g;
        }
    }

    float mi0 = 0.f, mi1 = 0.f;
#pragma unroll
    for (int mt = 0; mt < 2; mt++)
#pragma unroll
        for (int r = 0; r < 4; r++) { mi0 += accA[mt][0][r]; mi1 += accA[mt][1][r]; }
    mi0 += __shfl_xor(mi0, 16); mi0 += __shfl_xor(mi0, 32);
    mi1 += __shfl_xor(mi1, 16); mi1 += __shfl_xor(mi1, 32);
    if (lane < 16) { redm[wid][lane] = mi0; redm[wid][16 + lane] = mi1; }

    // smA reuse is safe: all hist use finished before the post-KNN __syncthreads,
    // and each wave reads/writes only its own smw slice below.
    unsigned short* smw = smA + wid * (32 * 32);
#pragma unroll
    for (int mt = 0; mt < 2; mt++)
#pragma unroll
        for (int nt = 0; nt < 2; nt++)
#pragma unroll
            for (int r = 0; r < 4; r++) {
                const int prow = (r << 3) | (4 * mt + q);
                smw[prow * 32 + nt * 16 + ln] = bf16_hu(accA[mt][nt][r]);
            }

    s16x8 a4[2];
#pragma unroll
    for (int mt = 0; mt < 2; mt++) {
        const int prow = ((ln & 3) << 3) | (4 * mt + (ln >> 2));
        a4[mt] = *(const s16x8*)(smw + prow * 32 + q * 8);
    }

    float cacc[2][4];
#pragma unroll
    for (int mt = 0; mt < 2; mt++)
#pragma unroll
        for (int r = 0; r < 4; r++) cacc[mt][r] = 0.f;

#pragma unroll
    for (int g = 0; g < 4; g++) {
        const float cb0 = sc1b[(2 * g + 0) * 16 + ln];
        const float cb1 = sc1b[(2 * g + 1) * 16 + ln];
        const f32x4 ci0 = {cb0, cb0, cb0, cb0};
        const f32x4 ci1 = {cb1, cb1, cb1, cb1};
        f32x4 c20[2], c21[2];
#pragma unroll
        for (int mt = 0; mt < 2; mt++) {
            c20[mt] = __builtin_amdgcn_mfma_f32_16x16x32_bf16(a4[mt], cfr[2 * g + 0], ci0, 0, 0, 0);
            c21[mt] = __builtin_amdgcn_mfma_f32_16x16x32_bf16(a4[mt], cfr[2 * g + 1], ci1, 0, 0, 0);
        }
#pragma unroll
        for (int h = 0; h < 2; h++) {
            const float c2wv = sc2w[(2 * g + h) * 16 + ln];
#pragma unroll
            for (int mt = 0; mt < 2; mt++)
#pragma unroll
                for (int r = 0; r < 4; r++) {
                    const float v = (h ? c21[mt][r] : c20[mt][r]);
                    cacc[mt][r] = fmaf(lrelu(v), c2wv, cacc[mt][r]);
                }
        }
    }
#pragma unroll
    for (int off = 1; off <= 8; off <<= 1)
#pragma unroll
        for (int mt = 0; mt < 2; mt++)
#pragma unroll
            for (int r = 0; r < 4; r++) cacc[mt][r] += __shfl_xor(cacc[mt][r], off);

    const float c2bv = c2b[0];
    float vxp = 0.f, vyp = 0.f;
    if (ln == 0) {
#pragma unroll
        for (int mt = 0; mt < 2; mt++)
#pragma unroll
            for (int r = 0; r < 4; r++) {
                const int row = rowbase + mt * 16 + q * 4 + r;
                const float cw = cacc[mt][r] + c2bv;
                vxp = fmaf(cw, su[row], vxp);
                vyp = fmaf(cw, sv[row], vyp);
            }
    }
    vxp += __shfl_xor(vxp, 16); vxp += __shfl_xor(vxp, 32);
    vyp += __shfl_xor(vyp, 16); vyp += __shfl_xor(vyp, 32);
    if (lane == 0) { redc[wid][0] = vxp; redc[wid][1] = vyp; }

    __syncthreads();
    if (t < DD) {
        sni[t] = sfi[t];
        sni[DD + t] = redm[0][t] + redm[1][t] + redm[2][t] + redm[3][t];
    }
    __syncthreads();
    {   // n1: 4-way K-split over 256 threads (16-FMA chains)
        const int o = t & 63, p = t >> 6;
        float a = 0.f;
#pragma unroll
        for (int k = 0; k < 16; k++) a = fmaf(sni[p * 16 + k], n1w[(p * 16 + k) * 64 + o], a);
        sp1[p][o] = a;
    }
    __syncthreads();
    if (t < 2 * DD)
        shd[t] = lrelu(n1b[t] + ((sp1[0][t] + sp1[1][t]) + (sp1[2][t] + sp1[3][t])));
    __syncthreads();
    if (t < 128) {   // n2: 4-way K-split over 128 threads
        const int o = t & 31, p = t >> 5;
        float a = 0.f;
#pragma unroll
        for (int k = 0; k < 16; k++) a = fmaf(shd[p * 16 + k], n2w[(p * 16 + k) * DD + o], a);
        sp2[p][o] = a;
    }
    __syncthreads();
    if (t < DD) {
        const float val = n2b[t] + ((sp2[0][t] + sp2[1][t]) + (sp2[2][t] + sp2[3][t])) + sfi[t];
        feats_out[node * DD + t] = val;
        sfo[t] = val;
    }
    if (t == 0) {
        coors_out[node * 2]     = cix + redc[0][0] + redc[1][0] + redc[2][0] + redc[3][0];
        coors_out[node * 2 + 1] = ciy + redc[0][1] + redc[1][1] + redc[2][1] + redc[3][1];
    }
    __syncthreads();

    // tail: next layer's HI/HJ for this node (node-local; double-buffered so no race)
    if (e1wn) {
        for (int idx = t; idx < 2 * EHP; idx += 256) {
            const int nl = idx / EHP, o = idx - nl * EHP;
            float* dst = (nl ? HJn : HIn) + (size_t)node * EHP + o;
            if (o >= EH) { *dst = 0.f; continue; }
            const int rowoff = nl ? DD : 0;
            float a = nl ? 0.f : e1bn[o];
#pragma unroll
            for (int k = 0; k < DD; k++) a = fmaf(sfo[k], e1wn[(rowoff + k) * EH + o], a);
            *dst = a;
        }
    }
}

extern "C" void kernel_launch(void* const* d_in, const int* in_sizes, int n_in,
                              void* d_out, int out_size, void* d_ws, size_t ws_size,
                              hipStream_t stream) {
    const float* feat_   = (const float*)d_in[0];
    const float* coor_   = (const float*)d_in[1];
    // d_in[2] = batch (int32, unused: equal-size graphs)
    const float* embed_w = (const float*)d_in[3];
    const float* embed_b = (const float*)d_in[4];
    const float* e1_w    = (const float*)d_in[5];
    const float* e1_b    = (const float*)d_in[6];
    const float* e2_w    = (const float*)d_in[7];
    const float* e2_b    = (const float*)d_in[8];
    const float* gate_w  = (const float*)d_in[9];
    const float* gate_b  = (const float*)d_in[10];
    const float* c1_w    = (const float*)d_in[11];
    const float* c1_b    = (const float*)d_in[12];
    const float* c2_w    = (const float*)d_in[13];
    const float* c2_b    = (const float*)d_in[14];
    const float* n1_w    = (const float*)d_in[15];
    const float* n1_b    = (const float*)d_in[16];
    const float* n2_w    = (const float*)d_in[17];
    const float* n2_b    = (const float*)d_in[18];
    const float* cscale  = (const float*)d_in[19];

    float* ws = (float*)d_ws;
    float* fa   = ws;   ws += BB * NN * DD;
    float* fb   = ws;   ws += BB * NN * DD;
    float* ca   = ws;   ws += BB * NN * 2;
    float* cb2  = ws;   ws += BB * NN * 2;
    float* HI0  = ws;   ws += BB * NN * EHP;
    float* HJ0  = ws;   ws += BB * NN * EHP;
    float* HI1  = ws;   ws += BB * NN * EHP;
    float* HJ1  = ws;   ws += BB * NN * EHP;
    unsigned short* e2f = (unsigned short*)ws;      // LL*5120 ushorts (5 K-chunks/layer)
    unsigned short* c1f = e2f + LL * 5120;          // LL*4096 ushorts

    // launch 1: embed + layer-0 HI/HJ + B-frags (all node-local / independent)
    prep_kernel<<<2048 + 96, 128, 0, stream>>>(feat_, embed_w, embed_b, fa,
                                               e1_w, e1_b, HI0, HJ0,
                                               e2_w, e2_b, c1_w, e2f, c1f);

    float* HIbuf[2] = {HI0, HI1};
    float* HJbuf[2] = {HJ0, HJ1};
    const float* fin = fa;
    const float* cin = coor_;
    float* fouts[LL] = {fb, fa, (float*)d_out};
    float* couts[LL] = {ca, cb2, ca};

    for (int l = 0; l < LL; l++) {
        const int cur = l & 1, nxt = (l + 1) & 1;
        layer_kernel<<<BB * NN, 256, 0, stream>>>(
            fin, cin, HIbuf[cur], HJbuf[cur],
            e1_w + ((size_t)l * 65 + 64) * EH,
            e2f + (size_t)l * 5120,
            c1f + (size_t)l * 4096,
            gate_w + (size_t)l * DD,
            gate_b + l,
            c1_b + (size_t)l * 128,
            c2_w + (size_t)l * 128,
            c2_b + l,
            n1_w + (size_t)l * 64 * 64,
            n1_b + (size_t)l * 64,
            n2_w + (size_t)l * 64 * 32,
            n2_b + (size_t)l * DD,
            cscale + l,
            (l < LL - 1) ? (e1_w + (size_t)(l + 1) * 65 * EH) : nullptr,
            (l < LL - 1) ? (e1_b + (size_t)(l + 1) * EH) : nullptr,
            HIbuf[nxt], HJbuf[nxt],
            fouts[l], couts[l]);
        fin = fouts[l];
        cin = couts[l];
    }
}